// Round 11
// baseline (208.211 us; speedup 1.0000x reference)
//
#include <hip/hip_runtime.h>
#include <cstdint>

typedef __attribute__((ext_vector_type(4))) int int32x4;
typedef __attribute__((ext_vector_type(16))) int int32x16;

#define GLOBAL_AS __attribute__((address_space(1)))
#define LDS_AS    __attribute__((address_space(3)))

// ---------------------------------------------------------------------------
// Kernel 0: pack int32-carried weight [N*K] (values in [-128,127]) to int8.
// ---------------------------------------------------------------------------
__global__ __launch_bounds__(256) void pack_w(
    const int* __restrict__ w32, uint32_t* __restrict__ w8_as_u32)
{
    const size_t i = (size_t)blockIdx.x * 256 + threadIdx.x; // 4 elems each
    const int4 v = ((const int4*)w32)[i];
    w8_as_u32[i] = (v.x & 0xff) | ((v.y & 0xff) << 8) |
                   ((v.z & 0xff) << 16) | ((uint32_t)(v.w & 0xff) << 24);
}

// ---------------------------------------------------------------------------
// Kernel 1: per-row dynamic symmetric int8 quantization (K=4096).
// ---------------------------------------------------------------------------
__global__ __launch_bounds__(256) void quant_rows(
    const float* __restrict__ in, int8_t* __restrict__ q,
    float* __restrict__ sa, int K)
{
    const int row = blockIdx.x;
    const float4* rp = (const float4*)(in + (size_t)row * K);
    const int t = threadIdx.x;

    float amax = 0.f;
    float4 v[4];
#pragma unroll
    for (int i = 0; i < 4; ++i) {
        v[i] = rp[t + (i << 8)];
        amax = fmaxf(amax,
               fmaxf(fmaxf(fabsf(v[i].x), fabsf(v[i].y)),
                     fmaxf(fabsf(v[i].z), fabsf(v[i].w))));
    }

#pragma unroll
    for (int off = 32; off; off >>= 1)
        amax = fmaxf(amax, __shfl_xor(amax, off));
    __shared__ float smax[4];
    if ((t & 63) == 0) smax[t >> 6] = amax;
    __syncthreads();
    amax = fmaxf(fmaxf(smax[0], smax[1]), fmaxf(smax[2], smax[3]));

    const float scale = (amax > 0.f) ? (amax / 127.f) : 1.f;
    if (t == 0) sa[row] = scale;
    const float rs = 1.f / scale;

    int* qrow = (int*)(q + (size_t)row * K);
#pragma unroll
    for (int i = 0; i < 4; ++i) {
        int a = __float2int_rn(v[i].x * rs);
        int b = __float2int_rn(v[i].y * rs);
        int c = __float2int_rn(v[i].z * rs);
        int d = __float2int_rn(v[i].w * rs);
        a = max(-128, min(127, a));
        b = max(-128, min(127, b));
        c = max(-128, min(127, c));
        d = max(-128, min(127, d));
        qrow[t + (i << 8)] = (a & 0xff) | ((b & 0xff) << 8) |
                             ((c & 0xff) << 16) | ((d & 0xff) << 24);
    }
}

// ---------------------------------------------------------------------------
// Kernel 2 (R11): R6 schedule EXACTLY (best measured: 156 us) with the only
// change being FRAGMENT-MAJOR LDS layout (R7/R8-verified 0-bank-conflict).
//
// Geometry: 256x256 tile, 4 waves x (128x128), mfma_i32_32x32x32_i8,
// ONE phase / ONE vmcnt(8) / ONE barrier per K-tile, ring-4 LDS (32 KiB
// K-tiles), stage-2-ahead, stage issued BETWEEN the two read batches (R6
// position; R10 showed stage-at-top costs ~6%).
//
// Fragment-major LDS tile (32 KiB): A region 16 KiB at offset 0:
//   frag(mblk,kk) contiguous 1 KiB at mblk*2048 + kk*1024, lane reads
//   base + lane*16 -> 0 conflicts (split-span reads cost 4 cyc/read,
//   measured R4/R5/R6). B region identical at +16384.
// Staging inverse map (LDS dest linear, rule #21), 8 loads/thread/tile:
//   srow = ((t>>7)&1)*32 + (t&31), scol16 = ((t>>6)&1)*2 + ((t>>5)&1),
//   c = 0..3 adds 64 rows (A and B regions each, dest + c*4096).
//
// Ledger: prologue stages tiles 0,1 (16 loads); vmcnt(8) -> tile0 landed;
// barrier. Iter g: read a0/b0 of tile g; stage tile g+2 into ring (g+2)&3;
// read a1/b1; 32 MFMA; vmcnt(8) -> tile g+1 landed (g+2's 8 in flight)
// [tail: vmcnt(0)]; barrier. WAR: slot (g+2)&3 last read iter g-2.
//
// Fragment maps (32x32 i8): A row = lane&31, k = (lane>>5)*16 + byte;
// B col = lane&31, same k. C/D: col = lane&31,
// row = (reg&3) + 8*(reg>>2) + 4*(lane>>5)  [guide-verified, dtype-indep].
// ---------------------------------------------------------------------------
__device__ __forceinline__ void async_load16(const int8_t* g, int8_t* lds) {
    __builtin_amdgcn_global_load_lds((const GLOBAL_AS char*)g,
                                     (LDS_AS char*)lds, 16, 0, 0);
}

__global__ __launch_bounds__(256, 1) void w8a8_gemm(
    const int8_t* __restrict__ Aq, const int8_t* __restrict__ W,
    const float* __restrict__ sa, const float* __restrict__ wsc,
    const float* __restrict__ bias, float* __restrict__ out,
    int M, int N, int K)
{
    __shared__ int8_t lds[4 * 32768]; // 128 KiB

    const int NB = N >> 8; // N/256
    const int nwg = gridDim.x;
    // XCD-aware strip swizzle (R6 exact; nwg % 8 == 0 -> bijective)
    const int cpx = nwg >> 3;
    const int wg = (blockIdx.x & 7) * cpx + (blockIdx.x >> 3);
    const int bm = wg / NB, bn = wg % NB;

    const int t = threadIdx.x;          // 0..255, 4 waves
    const int lane = t & 63, wid = t >> 6;
    const int wr = wid >> 1, wc = wid & 1;   // 2x2 wave grid, 128x128 each
    const int l31 = lane & 31, h = lane >> 5;

    // ---- staging: fragment-major inverse map, 8 loads/thread/tile ----
    const int srow = ((t >> 7) & 1) * 32 + (t & 31);          // 0..63
    const int scol = ((((t >> 6) & 1) * 2 + ((t >> 5) & 1)) << 4);
    const int8_t* gA = Aq + ((size_t)bm * 256 + srow) * (size_t)K + scol;
    const int8_t* gB = W  + ((size_t)bn * 256 + srow) * (size_t)K + scol;
    const size_t cstep = (size_t)64 * K;   // +64 rows per c
    int8_t* ldsw = &lds[t * 16];

    auto stage_tile = [&](int slot, int kbyte) {
        int8_t* d = ldsw + slot * 32768;
#pragma unroll
        for (int c = 0; c < 4; ++c) {
            async_load16(gA + c * cstep + kbyte, d + c * 4096);
            async_load16(gB + c * cstep + kbyte, d + 16384 + c * 4096);
        }
    };

    // ---- fragment read bases (contiguous: base + lane*16) ----
    const int aoff = wr * 8192 + lane * 16;          // + m*2048 (+1024 kk1)
    const int boff = 16384 + wc * 8192 + lane * 16;  // + n*2048 (+1024 kk1)

    int32x16 acc[4][4];
#pragma unroll
    for (int m = 0; m < 4; ++m)
#pragma unroll
        for (int n = 0; n < 4; ++n)
#pragma unroll
            for (int rgi = 0; rgi < 16; ++rgi)
                acc[m][n][rgi] = 0;

    const int NT = K >> 6; // 64 K-tiles

    // prologue: stage K-tiles 0 (ring 0) and 1 (ring 1)
    stage_tile(0, 0);
    stage_tile(1, 64);
    asm volatile("s_waitcnt vmcnt(8)" ::: "memory");
    asm volatile("s_barrier" ::: "memory");

    for (int g = 0; g < NT; ++g) {
        const int rbase = (g & 3) * 32768;

        int32x4 a0[4], b0[4], a1[4], b1[4];
#pragma unroll
        for (int m = 0; m < 4; ++m)
            a0[m] = *(const int32x4*)&lds[rbase + aoff + m * 2048];
#pragma unroll
        for (int n = 0; n < 4; ++n)
            b0[n] = *(const int32x4*)&lds[rbase + boff + n * 2048];

        if (g + 2 < NT) stage_tile((g + 2) & 3, (g + 2) << 6);

#pragma unroll
        for (int m = 0; m < 4; ++m)
            a1[m] = *(const int32x4*)&lds[rbase + aoff + m * 2048 + 1024];
#pragma unroll
        for (int n = 0; n < 4; ++n)
            b1[n] = *(const int32x4*)&lds[rbase + boff + n * 2048 + 1024];

#pragma unroll
        for (int m = 0; m < 4; ++m)
#pragma unroll
            for (int n = 0; n < 4; ++n)
                acc[m][n] = __builtin_amdgcn_mfma_i32_32x32x32_i8(
                    a0[m], b0[n], acc[m][n], 0, 0, 0);
#pragma unroll
        for (int m = 0; m < 4; ++m)
#pragma unroll
            for (int n = 0; n < 4; ++n)
                acc[m][n] = __builtin_amdgcn_mfma_i32_32x32x32_i8(
                    a1[m], b1[n], acc[m][n], 0, 0, 0);

        if (g < NT - 2)
            asm volatile("s_waitcnt vmcnt(8)" ::: "memory");
        else
            asm volatile("s_waitcnt vmcnt(0)" ::: "memory");
        asm volatile("s_barrier" ::: "memory");
    }

    // ---- epilogue: C/D col = lane&31, row = (reg&3)+8*(reg>>2)+4*h ----
    const int col0 = bn * 256 + wc * 128 + l31;      // + n*32
    const int row00 = bm * 256 + wr * 128 + 4 * h;   // + m*32 + (reg&3)+8*(reg>>2)

#pragma unroll
    for (int m = 0; m < 4; ++m) {
        float sv[16];
#pragma unroll
        for (int rgi = 0; rgi < 16; ++rgi)
            sv[rgi] = sa[row00 + m * 32 + (rgi & 3) + 8 * (rgi >> 2)];
#pragma unroll
        for (int n = 0; n < 4; ++n) {
            const int col = col0 + n * 32;
            const float wn = wsc[col];
            const float bb = bias[col];
#pragma unroll
            for (int rgi = 0; rgi < 16; ++rgi) {
                const int row = row00 + m * 32 + (rgi & 3) + 8 * (rgi >> 2);
                out[(size_t)row * N + col] =
                    (float)acc[m][n][rgi] * sv[rgi] * wn + bb;
            }
        }
    }
}

// ---------------------------------------------------------------------------
extern "C" void kernel_launch(void* const* d_in, const int* in_sizes, int n_in,
                              void* d_out, int out_size, void* d_ws, size_t ws_size,
                              hipStream_t stream) {
    const float* inp  = (const float*)d_in[0];
    const int*   w32  = (const int*)d_in[1];   // int8 values carried as int32
    const float* wsc  = (const float*)d_in[2];
    const float* bias = (const float*)d_in[3];
    float* out = (float*)d_out;

    const int N = in_sizes[2];            // 4096
    const int K = in_sizes[1] / N;        // 4096
    const int M = in_sizes[0] / K;        // 8192

    // workspace: q[M*K] i8 | sa[M] f32 | W8[N*K] i8
    int8_t* q  = (int8_t*)d_ws;
    float*  sa = (float*)((char*)d_ws + (size_t)M * K);
    int8_t* w8 = (int8_t*)((char*)d_ws + (size_t)M * K + (size_t)M * 4 + 256);

    const size_t nw4 = ((size_t)N * K) / 4;
    pack_w<<<(int)(nw4 / 256), 256, 0, stream>>>(w32, (uint32_t*)w8);

    quant_rows<<<M, 256, 0, stream>>>(inp, q, sa, K);

    const int nwg = (M / 256) * (N / 256); // 512
    w8a8_gemm<<<nwg, 256, 0, stream>>>(q, w8, sa, wsc, bias, out, M, N, K);
}

// Round 12
// 201.076 us; speedup vs baseline: 1.0355x; 1.0355x over previous
//
#include <hip/hip_runtime.h>
#include <cstdint>

typedef __attribute__((ext_vector_type(4))) int int32x4;
typedef __attribute__((ext_vector_type(16))) int int32x16;

#define GLOBAL_AS __attribute__((address_space(1)))
#define LDS_AS    __attribute__((address_space(3)))

// ---------------------------------------------------------------------------
// Kernel 0: pack int32-carried weight [N*K] (values in [-128,127]) to int8.
// ---------------------------------------------------------------------------
__global__ __launch_bounds__(256) void pack_w(
    const int* __restrict__ w32, uint32_t* __restrict__ w8_as_u32)
{
    const size_t i = (size_t)blockIdx.x * 256 + threadIdx.x; // 4 elems each
    const int4 v = ((const int4*)w32)[i];
    w8_as_u32[i] = (v.x & 0xff) | ((v.y & 0xff) << 8) |
                   ((v.z & 0xff) << 16) | ((uint32_t)(v.w & 0xff) << 24);
}

// ---------------------------------------------------------------------------
// Kernel 1: per-row dynamic symmetric int8 quantization (K=4096).
// ---------------------------------------------------------------------------
__global__ __launch_bounds__(256) void quant_rows(
    const float* __restrict__ in, int8_t* __restrict__ q,
    float* __restrict__ sa, int K)
{
    const int row = blockIdx.x;
    const float4* rp = (const float4*)(in + (size_t)row * K);
    const int t = threadIdx.x;

    float amax = 0.f;
    float4 v[4];
#pragma unroll
    for (int i = 0; i < 4; ++i) {
        v[i] = rp[t + (i << 8)];
        amax = fmaxf(amax,
               fmaxf(fmaxf(fabsf(v[i].x), fabsf(v[i].y)),
                     fmaxf(fabsf(v[i].z), fabsf(v[i].w))));
    }

#pragma unroll
    for (int off = 32; off; off >>= 1)
        amax = fmaxf(amax, __shfl_xor(amax, off));
    __shared__ float smax[4];
    if ((t & 63) == 0) smax[t >> 6] = amax;
    __syncthreads();
    amax = fmaxf(fmaxf(smax[0], smax[1]), fmaxf(smax[2], smax[3]));

    const float scale = (amax > 0.f) ? (amax / 127.f) : 1.f;
    if (t == 0) sa[row] = scale;
    const float rs = 1.f / scale;

    int* qrow = (int*)(q + (size_t)row * K);
#pragma unroll
    for (int i = 0; i < 4; ++i) {
        int a = __float2int_rn(v[i].x * rs);
        int b = __float2int_rn(v[i].y * rs);
        int c = __float2int_rn(v[i].z * rs);
        int d = __float2int_rn(v[i].w * rs);
        a = max(-128, min(127, a));
        b = max(-128, min(127, b));
        c = max(-128, min(127, c));
        d = max(-128, min(127, d));
        qrow[t + (i << 8)] = (a & 0xff) | ((b & 0xff) << 8) |
                             ((c & 0xff) << 16) | ((d & 0xff) << 24);
    }
}

// ---------------------------------------------------------------------------
// Kernel 2 (R12): R6 schedule verbatim, but BM x BN = 256 x 128 so TWO
// INDEPENDENT blocks fit per CU (separate barriers -> natural phase stagger;
// one block's MFMAs overlap the other's reads/DMA/barrier — the mechanism
// R8's same-block extra waves lacked due to the shared barrier).
//
// Geometry: 4 waves (2x2), each 128x64 output = 4m x 2n frags of 32x32,
// acc = 128 AGPR/wave -> ~220 regs -> 2 waves/SIMD with 2 blocks resident.
// LDS: 24 KiB/tile (A 256x64 = 16 KiB, B 128x64 = 8 KiB), ring-3 = 72 KiB
// -> 2 blocks = 144 KiB <= 160. Stage-2-ahead, counted vmcnt(6), one
// barrier per K-tile, stage issued between the two read batches (R6 pos).
//
// LDS map (R6 split-span + swizzle; the 4 cyc/read tax is cheaper than the
// scattered-global alternative, R11-measured): 16B-slot s of row r holds
// global slot s ^ P(r), P(r) = ((r>>1)^(r>>3)) & 3; applied on gload_lds
// GLOBAL source (dest linear, rule #21) and on ds_read address.
// Staging (6 loads/thread): A slots t+256c (c=0..3): row = t>>2 + 64c,
// col16 = swizzled t&3; B slots t+256c (c=0..1) at region +16384.
//
// Ledger: prologue stages tiles 0,1 (12 loads); vmcnt(6) -> tile0 landed;
// barrier. Iter g: read batch0 (kk=0) of tile g; stage tile g+2 into ring
// slot (g+2)%3 (WAR: held tile g-1, read at g-1, barrier passed); read
// batch1; 16 MFMA/wave; vmcnt(6) -> tile g+1 landed [tail vmcnt(0)]; barrier.
//
// Fragment maps (32x32 i8): A row = lane&31, k = (lane>>5)*16 + byte;
// B col = lane&31, same k. C/D: col = lane&31,
// row = (reg&3) + 8*(reg>>2) + 4*(lane>>5)  [guide-verified, dtype-indep].
// ---------------------------------------------------------------------------
__device__ __forceinline__ void async_load16(const int8_t* g, int8_t* lds) {
    __builtin_amdgcn_global_load_lds((const GLOBAL_AS char*)g,
                                     (LDS_AS char*)lds, 16, 0, 0);
}

__global__ __launch_bounds__(256, 2) void w8a8_gemm(
    const int8_t* __restrict__ Aq, const int8_t* __restrict__ W,
    const float* __restrict__ sa, const float* __restrict__ wsc,
    const float* __restrict__ bias, float* __restrict__ out,
    int M, int N, int K)
{
    __shared__ int8_t lds[3 * 24576]; // 72 KiB -> 2 blocks/CU

    const int NB = N >> 7; // N/128
    const int nwg = gridDim.x;
    // XCD-aware strip swizzle (nwg % 8 == 0 -> bijective)
    const int cpx = nwg >> 3;
    const int wg = (blockIdx.x & 7) * cpx + (blockIdx.x >> 3);
    const int bm = wg / NB, bn = wg % NB;

    const int t = threadIdx.x;          // 0..255, 4 waves
    const int lane = t & 63, wid = t >> 6;
    const int wr = wid >> 1, wc = wid & 1;   // waves: 2 row x 2 col (128x64)
    const int l31 = lane & 31, h = lane >> 5;
    const int pswz = ((lane >> 1) ^ (lane >> 3)) & 3;

    // ---- staging: R6 coalesced map (64B global segments), 6 loads/thread --
    const int srow = t >> 2;            // 0..63
    const int scol = (((t & 3) ^ ((t >> 3) & 3) ^ ((t >> 5) & 3)) << 4);
    const int8_t* gA = Aq + ((size_t)bm * 256 + srow) * (size_t)K + scol;
    const int8_t* gB = W  + ((size_t)bn * 128 + srow) * (size_t)K + scol;
    const size_t cstep = (size_t)64 * K;   // +64 rows per chunk
    int8_t* ldsw = &lds[t * 16];

    auto stage_tile = [&](int slot, int kbyte) {
        int8_t* d = ldsw + slot * 24576;
        async_load16(gA + kbyte,             d);
        async_load16(gA + cstep + kbyte,     d + 4096);
        async_load16(gA + 2 * cstep + kbyte, d + 8192);
        async_load16(gA + 3 * cstep + kbyte, d + 12288);
        async_load16(gB + kbyte,             d + 16384);
        async_load16(gB + cstep + kbyte,     d + 16384 + 4096);
    };

    // ---- fragment read bases (swizzled, R6 style) ----
    const int aoff = wr * 8192 + l31 * 64;          // + m*2048 + cs
    const int boff = 16384 + wc * 4096 + l31 * 64;  // + n*2048 + cs
    const int cs0 = ((0 + h) ^ pswz) << 4;          // kk = 0
    const int cs1 = ((2 + h) ^ pswz) << 4;          // kk = 1

    int32x16 acc[4][2];
#pragma unroll
    for (int m = 0; m < 4; ++m)
#pragma unroll
        for (int n = 0; n < 2; ++n)
#pragma unroll
            for (int rgi = 0; rgi < 16; ++rgi)
                acc[m][n][rgi] = 0;

    const int NT = K >> 6; // 64 K-tiles

    // prologue: stage tiles 0 (slot 0) and 1 (slot 1)
    stage_tile(0, 0);
    stage_tile(1, 64);
    asm volatile("s_waitcnt vmcnt(6)" ::: "memory");
    asm volatile("s_barrier" ::: "memory");

    int cur = 0, stg = 2; // ring-3 indices: tile g in slot cur, g+2 -> stg
    for (int g = 0; g < NT; ++g) {
        const int rbase = cur * 24576;

        int32x4 a0[4], b0[2], a1[4], b1[2];
#pragma unroll
        for (int m = 0; m < 4; ++m)
            a0[m] = *(const int32x4*)&lds[rbase + aoff + m * 2048 + cs0];
#pragma unroll
        for (int n = 0; n < 2; ++n)
            b0[n] = *(const int32x4*)&lds[rbase + boff + n * 2048 + cs0];

        if (g + 2 < NT) stage_tile(stg, (g + 2) << 6);

#pragma unroll
        for (int m = 0; m < 4; ++m)
            a1[m] = *(const int32x4*)&lds[rbase + aoff + m * 2048 + cs1];
#pragma unroll
        for (int n = 0; n < 2; ++n)
            b1[n] = *(const int32x4*)&lds[rbase + boff + n * 2048 + cs1];

#pragma unroll
        for (int m = 0; m < 4; ++m)
#pragma unroll
            for (int n = 0; n < 2; ++n)
                acc[m][n] = __builtin_amdgcn_mfma_i32_32x32x32_i8(
                    a0[m], b0[n], acc[m][n], 0, 0, 0);
#pragma unroll
        for (int m = 0; m < 4; ++m)
#pragma unroll
            for (int n = 0; n < 2; ++n)
                acc[m][n] = __builtin_amdgcn_mfma_i32_32x32x32_i8(
                    a1[m], b1[n], acc[m][n], 0, 0, 0);

        if (g < NT - 2)
            asm volatile("s_waitcnt vmcnt(6)" ::: "memory");
        else
            asm volatile("s_waitcnt vmcnt(0)" ::: "memory");
        asm volatile("s_barrier" ::: "memory");

        cur = (cur == 2) ? 0 : cur + 1;
        stg = (stg == 2) ? 0 : stg + 1;
    }

    // ---- epilogue: C/D col = lane&31, row = (reg&3)+8*(reg>>2)+4*h ----
    const int col0 = bn * 128 + wc * 64 + l31;       // + n*32
    const int row00 = bm * 256 + wr * 128 + 4 * h;   // + m*32 + (rgi&3)+8*(rgi>>2)

#pragma unroll
    for (int m = 0; m < 4; ++m) {
        float sv[16];
#pragma unroll
        for (int rgi = 0; rgi < 16; ++rgi)
            sv[rgi] = sa[row00 + m * 32 + (rgi & 3) + 8 * (rgi >> 2)];
#pragma unroll
        for (int n = 0; n < 2; ++n) {
            const int col = col0 + n * 32;
            const float wn = wsc[col];
            const float bb = bias[col];
#pragma unroll
            for (int rgi = 0; rgi < 16; ++rgi) {
                const int row = row00 + m * 32 + (rgi & 3) + 8 * (rgi >> 2);
                out[(size_t)row * N + col] =
                    (float)acc[m][n][rgi] * sv[rgi] * wn + bb;
            }
        }
    }
}

// ---------------------------------------------------------------------------
extern "C" void kernel_launch(void* const* d_in, const int* in_sizes, int n_in,
                              void* d_out, int out_size, void* d_ws, size_t ws_size,
                              hipStream_t stream) {
    const float* inp  = (const float*)d_in[0];
    const int*   w32  = (const int*)d_in[1];   // int8 values carried as int32
    const float* wsc  = (const float*)d_in[2];
    const float* bias = (const float*)d_in[3];
    float* out = (float*)d_out;

    const int N = in_sizes[2];            // 4096
    const int K = in_sizes[1] / N;        // 4096
    const int M = in_sizes[0] / K;        // 8192

    // workspace: q[M*K] i8 | sa[M] f32 | W8[N*K] i8
    int8_t* q  = (int8_t*)d_ws;
    float*  sa = (float*)((char*)d_ws + (size_t)M * K);
    int8_t* w8 = (int8_t*)((char*)d_ws + (size_t)M * K + (size_t)M * 4 + 256);

    const size_t nw4 = ((size_t)N * K) / 4;
    pack_w<<<(int)(nw4 / 256), 256, 0, stream>>>(w32, (uint32_t*)w8);

    quant_rows<<<M, 256, 0, stream>>>(inp, q, sa, K);

    const int nwg = (M / 256) * (N / 128); // 1024
    w8a8_gemm<<<nwg, 256, 0, stream>>>(q, w8, sa, wsc, bias, out, M, N, K);
}

// Round 13
// 200.137 us; speedup vs baseline: 1.0403x; 1.0047x over previous
//
#include <hip/hip_runtime.h>
#include <cstdint>

typedef __attribute__((ext_vector_type(4))) int int32x4;
typedef __attribute__((ext_vector_type(16))) int int32x16;

#define GLOBAL_AS __attribute__((address_space(1)))
#define LDS_AS    __attribute__((address_space(3)))

// ---------------------------------------------------------------------------
// Kernel 1 (merged prep): blocks [0,M) quantize rows; blocks [M, M+NP) pack
// the int32-carried weight to int8. Both memory-bound; one launch, overlapped.
// ---------------------------------------------------------------------------
__global__ __launch_bounds__(256) void prep(
    const float* __restrict__ in, int8_t* __restrict__ q,
    float* __restrict__ sa, int K, int Mrows,
    const int* __restrict__ w32, uint32_t* __restrict__ w8_as_u32)
{
    const int t = threadIdx.x;

    if ((int)blockIdx.x >= Mrows) {
        // ---- pack branch: 4 int32 -> 4 int8 per thread ----
        const size_t i = (size_t)(blockIdx.x - Mrows) * 256 + t;
        const int4 v = ((const int4*)w32)[i];
        w8_as_u32[i] = (v.x & 0xff) | ((v.y & 0xff) << 8) |
                       ((v.z & 0xff) << 16) | ((uint32_t)(v.w & 0xff) << 24);
        return;
    }

    // ---- quant branch: one block per row, K = 4096 ----
    const int row = blockIdx.x;
    const float4* rp = (const float4*)(in + (size_t)row * K);

    float amax = 0.f;
    float4 v[4];
#pragma unroll
    for (int i = 0; i < 4; ++i) {
        v[i] = rp[t + (i << 8)];
        amax = fmaxf(amax,
               fmaxf(fmaxf(fabsf(v[i].x), fabsf(v[i].y)),
                     fmaxf(fabsf(v[i].z), fabsf(v[i].w))));
    }

#pragma unroll
    for (int off = 32; off; off >>= 1)
        amax = fmaxf(amax, __shfl_xor(amax, off));
    __shared__ float smax[4];
    if ((t & 63) == 0) smax[t >> 6] = amax;
    __syncthreads();
    amax = fmaxf(fmaxf(smax[0], smax[1]), fmaxf(smax[2], smax[3]));

    const float scale = (amax > 0.f) ? (amax / 127.f) : 1.f;
    if (t == 0) sa[row] = scale;
    const float rs = 1.f / scale;

    int* qrow = (int*)(q + (size_t)row * K);
#pragma unroll
    for (int i = 0; i < 4; ++i) {
        int a = __float2int_rn(v[i].x * rs);
        int b = __float2int_rn(v[i].y * rs);
        int c = __float2int_rn(v[i].z * rs);
        int d = __float2int_rn(v[i].w * rs);
        a = max(-128, min(127, a));
        b = max(-128, min(127, b));
        c = max(-128, min(127, c));
        d = max(-128, min(127, d));
        qrow[t + (i << 8)] = (a & 0xff) | ((b & 0xff) << 8) |
                             ((c & 0xff) << 16) | ((d & 0xff) << 24);
    }
}

// ---------------------------------------------------------------------------
// Kernel 2 (R13): R12 verbatim (best measured: 153.5 us GEMM) + T5 setprio
// around the MFMA cluster. R12 has genuine cross-block role diversity
// (2 independent blocks/CU, separate barriers) — the regime where setprio
// pays (m190's null was same-block lockstep).
//
// Geometry: BM x BN = 256 x 128, 4 waves (2x2), each 128x64 = 4m x 2n frags
// of 32x32, acc 128 AGPR (combined ~228 regs -> 2 waves/SIMD, 2 blocks/CU).
// LDS: 24 KiB/tile (A 16 + B 8), ring-3 = 72 KiB. Stage-2-ahead, counted
// vmcnt(6), one barrier per K-tile, stage between the two read batches.
//
// LDS map: R6 split-span + swizzle (4 cyc/read tax, cheaper than scattered
// global DMA per R11): 16B-slot s of row r holds global slot s ^ P(r),
// P(r) = ((r>>1)^(r>>3)) & 3; applied on gload_lds GLOBAL source (dest
// linear, rule #21) and on ds_read address.
//
// Ledger: prologue stages tiles 0,1 (12 loads); vmcnt(6) -> tile0 landed;
// barrier. Iter g: read batch0; stage tile g+2 into ring slot (g+2)%3;
// read batch1; setprio(1) 16 MFMA setprio(0); vmcnt(6) [tail vmcnt(0)];
// barrier. WAR: stage slot held tile g-1, read completed at g-1's barrier.
//
// Fragment maps (32x32 i8): A row = lane&31, k = (lane>>5)*16 + byte;
// B col = lane&31, same k. C/D: col = lane&31,
// row = (reg&3) + 8*(reg>>2) + 4*(lane>>5)  [guide-verified, dtype-indep].
// ---------------------------------------------------------------------------
__device__ __forceinline__ void async_load16(const int8_t* g, int8_t* lds) {
    __builtin_amdgcn_global_load_lds((const GLOBAL_AS char*)g,
                                     (LDS_AS char*)lds, 16, 0, 0);
}

__global__ __launch_bounds__(256, 2) void w8a8_gemm(
    const int8_t* __restrict__ Aq, const int8_t* __restrict__ W,
    const float* __restrict__ sa, const float* __restrict__ wsc,
    const float* __restrict__ bias, float* __restrict__ out,
    int M, int N, int K)
{
    __shared__ int8_t lds[3 * 24576]; // 72 KiB -> 2 blocks/CU

    const int NB = N >> 7; // N/128
    const int nwg = gridDim.x;
    // XCD-aware strip swizzle (nwg % 8 == 0 -> bijective)
    const int cpx = nwg >> 3;
    const int wg = (blockIdx.x & 7) * cpx + (blockIdx.x >> 3);
    const int bm = wg / NB, bn = wg % NB;

    const int t = threadIdx.x;          // 0..255, 4 waves
    const int lane = t & 63, wid = t >> 6;
    const int wr = wid >> 1, wc = wid & 1;   // waves: 2 row x 2 col (128x64)
    const int l31 = lane & 31, h = lane >> 5;
    const int pswz = ((lane >> 1) ^ (lane >> 3)) & 3;

    // ---- staging: R6 coalesced map (64B global segments), 6 loads/thread --
    const int srow = t >> 2;            // 0..63
    const int scol = (((t & 3) ^ ((t >> 3) & 3) ^ ((t >> 5) & 3)) << 4);
    const int8_t* gA = Aq + ((size_t)bm * 256 + srow) * (size_t)K + scol;
    const int8_t* gB = W  + ((size_t)bn * 128 + srow) * (size_t)K + scol;
    const size_t cstep = (size_t)64 * K;   // +64 rows per chunk
    int8_t* ldsw = &lds[t * 16];

    auto stage_tile = [&](int slot, int kbyte) {
        int8_t* d = ldsw + slot * 24576;
        async_load16(gA + kbyte,             d);
        async_load16(gA + cstep + kbyte,     d + 4096);
        async_load16(gA + 2 * cstep + kbyte, d + 8192);
        async_load16(gA + 3 * cstep + kbyte, d + 12288);
        async_load16(gB + kbyte,             d + 16384);
        async_load16(gB + cstep + kbyte,     d + 16384 + 4096);
    };

    // ---- fragment read bases (swizzled) ----
    const int aoff = wr * 8192 + l31 * 64;          // + m*2048 + cs
    const int boff = 16384 + wc * 4096 + l31 * 64;  // + n*2048 + cs
    const int cs0 = ((0 + h) ^ pswz) << 4;          // kk = 0
    const int cs1 = ((2 + h) ^ pswz) << 4;          // kk = 1

    int32x16 acc[4][2];
#pragma unroll
    for (int m = 0; m < 4; ++m)
#pragma unroll
        for (int n = 0; n < 2; ++n)
#pragma unroll
            for (int rgi = 0; rgi < 16; ++rgi)
                acc[m][n][rgi] = 0;

    const int NT = K >> 6; // 64 K-tiles

    // prologue: stage tiles 0 (slot 0) and 1 (slot 1)
    stage_tile(0, 0);
    stage_tile(1, 64);
    asm volatile("s_waitcnt vmcnt(6)" ::: "memory");
    asm volatile("s_barrier" ::: "memory");

    int cur = 0, stg = 2; // ring-3 indices: tile g in slot cur, g+2 -> stg
    for (int g = 0; g < NT; ++g) {
        const int rbase = cur * 24576;

        int32x4 a0[4], b0[2], a1[4], b1[2];
#pragma unroll
        for (int m = 0; m < 4; ++m)
            a0[m] = *(const int32x4*)&lds[rbase + aoff + m * 2048 + cs0];
#pragma unroll
        for (int n = 0; n < 2; ++n)
            b0[n] = *(const int32x4*)&lds[rbase + boff + n * 2048 + cs0];

        if (g + 2 < NT) stage_tile(stg, (g + 2) << 6);

#pragma unroll
        for (int m = 0; m < 4; ++m)
            a1[m] = *(const int32x4*)&lds[rbase + aoff + m * 2048 + cs1];
#pragma unroll
        for (int n = 0; n < 2; ++n)
            b1[n] = *(const int32x4*)&lds[rbase + boff + n * 2048 + cs1];

        __builtin_amdgcn_s_setprio(1);
#pragma unroll
        for (int m = 0; m < 4; ++m)
#pragma unroll
            for (int n = 0; n < 2; ++n)
                acc[m][n] = __builtin_amdgcn_mfma_i32_32x32x32_i8(
                    a0[m], b0[n], acc[m][n], 0, 0, 0);
#pragma unroll
        for (int m = 0; m < 4; ++m)
#pragma unroll
            for (int n = 0; n < 2; ++n)
                acc[m][n] = __builtin_amdgcn_mfma_i32_32x32x32_i8(
                    a1[m], b1[n], acc[m][n], 0, 0, 0);
        __builtin_amdgcn_s_setprio(0);

        if (g < NT - 2)
            asm volatile("s_waitcnt vmcnt(6)" ::: "memory");
        else
            asm volatile("s_waitcnt vmcnt(0)" ::: "memory");
        asm volatile("s_barrier" ::: "memory");

        cur = (cur == 2) ? 0 : cur + 1;
        stg = (stg == 2) ? 0 : stg + 1;
    }

    // ---- epilogue: C/D col = lane&31, row = (reg&3)+8*(reg>>2)+4*h ----
    const int col0 = bn * 128 + wc * 64 + l31;       // + n*32
    const int row00 = bm * 256 + wr * 128 + 4 * h;   // + m*32 + (rgi&3)+8*(rgi>>2)

#pragma unroll
    for (int m = 0; m < 4; ++m) {
        float sv[16];
#pragma unroll
        for (int rgi = 0; rgi < 16; ++rgi)
            sv[rgi] = sa[row00 + m * 32 + (rgi & 3) + 8 * (rgi >> 2)];
#pragma unroll
        for (int n = 0; n < 2; ++n) {
            const int col = col0 + n * 32;
            const float wn = wsc[col];
            const float bb = bias[col];
#pragma unroll
            for (int rgi = 0; rgi < 16; ++rgi) {
                const int row = row00 + m * 32 + (rgi & 3) + 8 * (rgi >> 2);
                out[(size_t)row * N + col] =
                    (float)acc[m][n][rgi] * sv[rgi] * wn + bb;
            }
        }
    }
}

// ---------------------------------------------------------------------------
extern "C" void kernel_launch(void* const* d_in, const int* in_sizes, int n_in,
                              void* d_out, int out_size, void* d_ws, size_t ws_size,
                              hipStream_t stream) {
    const float* inp  = (const float*)d_in[0];
    const int*   w32  = (const int*)d_in[1];   // int8 values carried as int32
    const float* wsc  = (const float*)d_in[2];
    const float* bias = (const float*)d_in[3];
    float* out = (float*)d_out;

    const int N = in_sizes[2];            // 4096
    const int K = in_sizes[1] / N;        // 4096
    const int M = in_sizes[0] / K;        // 8192

    // workspace: q[M*K] i8 | sa[M] f32 | W8[N*K] i8
    int8_t* q  = (int8_t*)d_ws;
    float*  sa = (float*)((char*)d_ws + (size_t)M * K);
    int8_t* w8 = (int8_t*)((char*)d_ws + (size_t)M * K + (size_t)M * 4 + 256);

    const int pack_blocks = (int)(((size_t)N * K) / 4 / 256); // 16384
    prep<<<M + pack_blocks, 256, 0, stream>>>(inp, q, sa, K, M,
                                              w32, (uint32_t*)w8);

    const int nwg = (M / 256) * (N / 128); // 1024
    w8a8_gemm<<<nwg, 256, 0, stream>>>(q, w8, sa, wsc, bias, out, M, N, K);
}

// Round 14
// 196.840 us; speedup vs baseline: 1.0578x; 1.0167x over previous
//
#include <hip/hip_runtime.h>
#include <cstdint>

typedef __attribute__((ext_vector_type(4))) int int32x4;
typedef __attribute__((ext_vector_type(16))) int int32x16;

#define GLOBAL_AS __attribute__((address_space(1)))
#define LDS_AS    __attribute__((address_space(3)))

// ---------------------------------------------------------------------------
// Kernel 1 (merged prep): blocks [0,M) quantize rows; blocks [M, M+NP) pack
// the int32-carried weight to int8. Both memory-bound; one launch, overlapped.
// (R13-measured: ~40 us vs 47.6 us for the two separate launches.)
// ---------------------------------------------------------------------------
__global__ __launch_bounds__(256) void prep(
    const float* __restrict__ in, int8_t* __restrict__ q,
    float* __restrict__ sa, int K, int Mrows,
    const int* __restrict__ w32, uint32_t* __restrict__ w8_as_u32)
{
    const int t = threadIdx.x;

    if ((int)blockIdx.x >= Mrows) {
        // ---- pack branch: 4 int32 -> 4 int8 per thread ----
        const size_t i = (size_t)(blockIdx.x - Mrows) * 256 + t;
        const int4 v = ((const int4*)w32)[i];
        w8_as_u32[i] = (v.x & 0xff) | ((v.y & 0xff) << 8) |
                       ((v.z & 0xff) << 16) | ((uint32_t)(v.w & 0xff) << 24);
        return;
    }

    // ---- quant branch: one block per row, K = 4096 ----
    const int row = blockIdx.x;
    const float4* rp = (const float4*)(in + (size_t)row * K);

    float amax = 0.f;
    float4 v[4];
#pragma unroll
    for (int i = 0; i < 4; ++i) {
        v[i] = rp[t + (i << 8)];
        amax = fmaxf(amax,
               fmaxf(fmaxf(fabsf(v[i].x), fabsf(v[i].y)),
                     fmaxf(fabsf(v[i].z), fabsf(v[i].w))));
    }

#pragma unroll
    for (int off = 32; off; off >>= 1)
        amax = fmaxf(amax, __shfl_xor(amax, off));
    __shared__ float smax[4];
    if ((t & 63) == 0) smax[t >> 6] = amax;
    __syncthreads();
    amax = fmaxf(fmaxf(smax[0], smax[1]), fmaxf(smax[2], smax[3]));

    const float scale = (amax > 0.f) ? (amax / 127.f) : 1.f;
    if (t == 0) sa[row] = scale;
    const float rs = 1.f / scale;

    int* qrow = (int*)(q + (size_t)row * K);
#pragma unroll
    for (int i = 0; i < 4; ++i) {
        int a = __float2int_rn(v[i].x * rs);
        int b = __float2int_rn(v[i].y * rs);
        int c = __float2int_rn(v[i].z * rs);
        int d = __float2int_rn(v[i].w * rs);
        a = max(-128, min(127, a));
        b = max(-128, min(127, b));
        c = max(-128, min(127, c));
        d = max(-128, min(127, d));
        qrow[t + (i << 8)] = (a & 0xff) | ((b & 0xff) << 8) |
                             ((c & 0xff) << 16) | ((d & 0xff) << 24);
    }
}

// ---------------------------------------------------------------------------
// Kernel 2 (R14 = R12 GEMM verbatim; best measured 153.5 us, MfmaUtil 41.8%).
// R13's setprio experiment REGRESSED (-4%: boosting MFMA-phase waves starved
// the sibling block's DMA issue on the shared CU) — reverted.
//
// Geometry: BM x BN = 256 x 128, 4 waves (2x2), each 128x64 = 4m x 2n frags
// of 32x32, acc 128 AGPR (~220 regs -> 2 waves/SIMD, 2 independent
// blocks/CU -> cross-block phase stagger, the only structure measured to
// beat R6's 1-block layout).
// LDS: 24 KiB/tile (A 16 + B 8), ring-3 = 72 KiB. Stage-2-ahead, counted
// vmcnt(6), one barrier per K-tile, stage between the two read batches.
//
// LDS map: split-span + swizzle (4 cyc/read tax; cheaper than the
// scattered-global fragment-major alternative, R11-measured): 16B-slot s of
// row r holds global slot s ^ P(r), P(r) = ((r>>1)^(r>>3)) & 3; applied on
// gload_lds GLOBAL source (dest linear, rule #21) and on ds_read address.
//
// Ledger: prologue stages tiles 0,1 (12 loads); vmcnt(6) -> tile0 landed;
// barrier. Iter g: read batch0; stage tile g+2 into ring slot (g+2)%3;
// read batch1; 16 MFMA; vmcnt(6) -> tile g+1 landed [tail vmcnt(0)];
// barrier. WAR: stage slot held tile g-1, whose reads completed at g-1's
// barrier.
//
// Fragment maps (32x32 i8): A row = lane&31, k = (lane>>5)*16 + byte;
// B col = lane&31, same k. C/D: col = lane&31,
// row = (reg&3) + 8*(reg>>2) + 4*(lane>>5)  [guide-verified, dtype-indep].
// ---------------------------------------------------------------------------
__device__ __forceinline__ void async_load16(const int8_t* g, int8_t* lds) {
    __builtin_amdgcn_global_load_lds((const GLOBAL_AS char*)g,
                                     (LDS_AS char*)lds, 16, 0, 0);
}

__global__ __launch_bounds__(256, 2) void w8a8_gemm(
    const int8_t* __restrict__ Aq, const int8_t* __restrict__ W,
    const float* __restrict__ sa, const float* __restrict__ wsc,
    const float* __restrict__ bias, float* __restrict__ out,
    int M, int N, int K)
{
    __shared__ int8_t lds[3 * 24576]; // 72 KiB -> 2 blocks/CU

    const int NB = N >> 7; // N/128
    const int nwg = gridDim.x;
    // XCD-aware strip swizzle (nwg % 8 == 0 -> bijective)
    const int cpx = nwg >> 3;
    const int wg = (blockIdx.x & 7) * cpx + (blockIdx.x >> 3);
    const int bm = wg / NB, bn = wg % NB;

    const int t = threadIdx.x;          // 0..255, 4 waves
    const int lane = t & 63, wid = t >> 6;
    const int wr = wid >> 1, wc = wid & 1;   // waves: 2 row x 2 col (128x64)
    const int l31 = lane & 31, h = lane >> 5;
    const int pswz = ((lane >> 1) ^ (lane >> 3)) & 3;

    // ---- staging: coalesced map (64B global segments), 6 loads/thread ----
    const int srow = t >> 2;            // 0..63
    const int scol = (((t & 3) ^ ((t >> 3) & 3) ^ ((t >> 5) & 3)) << 4);
    const int8_t* gA = Aq + ((size_t)bm * 256 + srow) * (size_t)K + scol;
    const int8_t* gB = W  + ((size_t)bn * 128 + srow) * (size_t)K + scol;
    const size_t cstep = (size_t)64 * K;   // +64 rows per chunk
    int8_t* ldsw = &lds[t * 16];

    auto stage_tile = [&](int slot, int kbyte) {
        int8_t* d = ldsw + slot * 24576;
        async_load16(gA + kbyte,             d);
        async_load16(gA + cstep + kbyte,     d + 4096);
        async_load16(gA + 2 * cstep + kbyte, d + 8192);
        async_load16(gA + 3 * cstep + kbyte, d + 12288);
        async_load16(gB + kbyte,             d + 16384);
        async_load16(gB + cstep + kbyte,     d + 16384 + 4096);
    };

    // ---- fragment read bases (swizzled) ----
    const int aoff = wr * 8192 + l31 * 64;          // + m*2048 + cs
    const int boff = 16384 + wc * 4096 + l31 * 64;  // + n*2048 + cs
    const int cs0 = ((0 + h) ^ pswz) << 4;          // kk = 0
    const int cs1 = ((2 + h) ^ pswz) << 4;          // kk = 1

    int32x16 acc[4][2];
#pragma unroll
    for (int m = 0; m < 4; ++m)
#pragma unroll
        for (int n = 0; n < 2; ++n)
#pragma unroll
            for (int rgi = 0; rgi < 16; ++rgi)
                acc[m][n][rgi] = 0;

    const int NT = K >> 6; // 64 K-tiles

    // prologue: stage tiles 0 (slot 0) and 1 (slot 1)
    stage_tile(0, 0);
    stage_tile(1, 64);
    asm volatile("s_waitcnt vmcnt(6)" ::: "memory");
    asm volatile("s_barrier" ::: "memory");

    int cur = 0, stg = 2; // ring-3 indices: tile g in slot cur, g+2 -> stg
    for (int g = 0; g < NT; ++g) {
        const int rbase = cur * 24576;

        int32x4 a0[4], b0[2], a1[4], b1[2];
#pragma unroll
        for (int m = 0; m < 4; ++m)
            a0[m] = *(const int32x4*)&lds[rbase + aoff + m * 2048 + cs0];
#pragma unroll
        for (int n = 0; n < 2; ++n)
            b0[n] = *(const int32x4*)&lds[rbase + boff + n * 2048 + cs0];

        if (g + 2 < NT) stage_tile(stg, (g + 2) << 6);

#pragma unroll
        for (int m = 0; m < 4; ++m)
            a1[m] = *(const int32x4*)&lds[rbase + aoff + m * 2048 + cs1];
#pragma unroll
        for (int n = 0; n < 2; ++n)
            b1[n] = *(const int32x4*)&lds[rbase + boff + n * 2048 + cs1];

#pragma unroll
        for (int m = 0; m < 4; ++m)
#pragma unroll
            for (int n = 0; n < 2; ++n)
                acc[m][n] = __builtin_amdgcn_mfma_i32_32x32x32_i8(
                    a0[m], b0[n], acc[m][n], 0, 0, 0);
#pragma unroll
        for (int m = 0; m < 4; ++m)
#pragma unroll
            for (int n = 0; n < 2; ++n)
                acc[m][n] = __builtin_amdgcn_mfma_i32_32x32x32_i8(
                    a1[m], b1[n], acc[m][n], 0, 0, 0);

        if (g < NT - 2)
            asm volatile("s_waitcnt vmcnt(6)" ::: "memory");
        else
            asm volatile("s_waitcnt vmcnt(0)" ::: "memory");
        asm volatile("s_barrier" ::: "memory");

        cur = (cur == 2) ? 0 : cur + 1;
        stg = (stg == 2) ? 0 : stg + 1;
    }

    // ---- epilogue: C/D col = lane&31, row = (reg&3)+8*(reg>>2)+4*h ----
    const int col0 = bn * 128 + wc * 64 + l31;       // + n*32
    const int row00 = bm * 256 + wr * 128 + 4 * h;   // + m*32 + (rgi&3)+8*(rgi>>2)

#pragma unroll
    for (int m = 0; m < 4; ++m) {
        float sv[16];
#pragma unroll
        for (int rgi = 0; rgi < 16; ++rgi)
            sv[rgi] = sa[row00 + m * 32 + (rgi & 3) + 8 * (rgi >> 2)];
#pragma unroll
        for (int n = 0; n < 2; ++n) {
            const int col = col0 + n * 32;
            const float wn = wsc[col];
            const float bb = bias[col];
#pragma unroll
            for (int rgi = 0; rgi < 16; ++rgi) {
                const int row = row00 + m * 32 + (rgi & 3) + 8 * (rgi >> 2);
                out[(size_t)row * N + col] =
                    (float)acc[m][n][rgi] * sv[rgi] * wn + bb;
            }
        }
    }
}

// ---------------------------------------------------------------------------
extern "C" void kernel_launch(void* const* d_in, const int* in_sizes, int n_in,
                              void* d_out, int out_size, void* d_ws, size_t ws_size,
                              hipStream_t stream) {
    const float* inp  = (const float*)d_in[0];
    const int*   w32  = (const int*)d_in[1];   // int8 values carried as int32
    const float* wsc  = (const float*)d_in[2];
    const float* bias = (const float*)d_in[3];
    float* out = (float*)d_out;

    const int N = in_sizes[2];            // 4096
    const int K = in_sizes[1] / N;        // 4096
    const int M = in_sizes[0] / K;        // 8192

    // workspace: q[M*K] i8 | sa[M] f32 | W8[N*K] i8
    int8_t* q  = (int8_t*)d_ws;
    float*  sa = (float*)((char*)d_ws + (size_t)M * K);
    int8_t* w8 = (int8_t*)((char*)d_ws + (size_t)M * K + (size_t)M * 4 + 256);

    const int pack_blocks = (int)(((size_t)N * K) / 4 / 256); // 16384
    prep<<<M + pack_blocks, 256, 0, stream>>>(inp, q, sa, K, M,
                                              w32, (uint32_t*)w8);

    const int nwg = (M / 256) * (N / 128); // 1024
    w8a8_gemm<<<nwg, 256, 0, stream>>>(q, w8, sa, wsc, bias, out, M, N, K);
}